// Round 14
// baseline (224.164 us; speedup 1.0000x reference)
//
#include <hip/hip_runtime.h>

// Sparse conv block, output-major, int32 exch-chain (round 14):
//   aux pipeline identical to round 13 (proven); conv re-tiled for concurrency:
//   64 rows/block (grid 1564 = 6.1 blocks/CU, ~24 waves/CU), one row per wave
//   per k, DEPTH-3 row prefetch (st[4][2], depth-4 idx), no launch-bounds cap,
//   W[k] LDS dbuf + XOR-swizzle, LBAR barrier, fused BN stats.
//   init / build / compact / fixup / norm unchanged.    MI355X / gfx950.

#define N_VOX   100000
#define NPAD    100096                  // multiple of 64
#define K3      27
#define M_PAIRS 40000
#define NPAIRS  (K3 * M_PAIRS)          // 1,080,000
#define BN_EPS  1e-5f
#define NBINS   (K3 * NPAD)             // 2,702,592
#define AUXMAX  184320                  // E[cnt>=2 bins] = 166.2k
#define AUXCAP  (AUXMAX - 1)
#define ZROW    (N_VOX + AUXMAX - 1)    // zeroed gather row (empty bins)

// ---- workspace layout (bytes) — round-11/13 proven fit ----------------------
#define OFF_WT     0u                       // bf16 Wt[k][c][i]        221,184
#define OFF_STATS  221184u                  // f32[128]
#define OFF_CTRS   221696u                  // [0]=aux counter
#define OFF_GINX   221760u                  // int ginx[NBINS]      10,810,368
#define OFF_NODE   11032128u                // int2 node[NPAIRS]     8,640,000
#define OFF_LIST   19672128u                // int list[AUXMAX]        737,280
#define OFF_XB     20409472u                // bf16 rows[N_VOX+AUXMAX][64]
// bh aliased into xb's AUX region (dead after compact; fixup writes aux slots
// only after compact; ZROW is far beyond bh's end)
#define OFF_BH     (OFF_XB + 12800000u)     // int bh[NBINS]        10,810,368
#define WS_NEED    ((size_t)OFF_XB + (size_t)(N_VOX + AUXMAX) * 128u)

#define NB_WT    432                    // 27*4096/256
#define NB_XB    3125                   // ceil(N_VOX*8/256)
#define GRID_IN  (NB_WT + NB_XB + 1)    // 3558
#define NB_BUILD 4219                   // ceil(NPAIRS/256)

typedef __attribute__((ext_vector_type(8))) short bf16x8;
typedef __attribute__((ext_vector_type(4))) float f32x4;

// LDS-ordering-only barrier: global loads (vmcnt) stay in flight across the
// barrier; compiler still inserts vmcnt(N) before each consuming MFMA.
#define LBAR() asm volatile("s_waitcnt lgkmcnt(0)\n\ts_barrier" ::: "memory")

__device__ __forceinline__ short f2bf(float f) {
  unsigned u = __builtin_bit_cast(unsigned, f);
  u += 0x7FFFu + ((u >> 16) & 1u);
  return (short)(u >> 16);
}
__device__ __forceinline__ float bf2f(short s) {
  unsigned u = ((unsigned)(unsigned short)s) << 16;
  return __builtin_bit_cast(float, u);
}

// ---- init: pure streaming ---------------------------------------------------
__global__ __launch_bounds__(256) void init_kernel(const float* __restrict__ W,
                                                   const float* __restrict__ x,
                                                   short* __restrict__ wt,
                                                   short* __restrict__ xb) {
  int b = blockIdx.x, t = threadIdx.x;
  if (b < NB_WT) {
    int id = b * 256 + t;
    int k = id >> 12, rem = id & 4095, c = rem >> 6, i = rem & 63;
    wt[id] = f2bf(W[(k << 12) + (i << 6) + c]);     // wt[k][c][i]
  } else if (b < NB_WT + NB_XB) {
    int id = (b - NB_WT) * 256 + t;
    if (id < N_VOX * 8) {
      float4 lo = ((const float4*)x)[id * 2];
      float4 hi = ((const float4*)x)[id * 2 + 1];
      bf16x8 v;
      v[0] = f2bf(lo.x); v[1] = f2bf(lo.y); v[2] = f2bf(lo.z); v[3] = f2bf(lo.w);
      v[4] = f2bf(hi.x); v[5] = f2bf(hi.y); v[6] = f2bf(hi.z); v[7] = f2bf(hi.w);
      ((bf16x8*)xb)[id] = v;
    }
  } else {
    if (t < 8) {
      bf16x8 z = {0, 0, 0, 0, 0, 0, 0, 0};
      ((bf16x8*)(xb + (size_t)ZROW * 64))[t] = z;
    }
  }
}

// ---- build: atomics only, int32 heads (L2-resident working window) ----------
__global__ __launch_bounds__(256) void build_kernel(const int* __restrict__ in_idx,
                                                    const int* __restrict__ out_idx,
                                                    int* __restrict__ bh,
                                                    int2* __restrict__ node) {
  int id = blockIdx.x * 256 + threadIdx.x;
  if (id >= NPAIRS) return;
  int k  = id / M_PAIRS;
  int in = in_idx[id];
  int o  = out_idx[id];
  int bb = k * NPAD + o;
  int old = atomicExch(&bh[bb], id);
  node[id] = make_int2(old, in);                // {prev, in}, coalesced
}

// ---- compact: coalesced head read; 1 scattered node read per non-empty bin --
__global__ __launch_bounds__(256) void compact_kernel(const int* __restrict__ bh,
                                                      const int2* __restrict__ node,
                                                      int* __restrict__ ginx,
                                                      int* __restrict__ list,
                                                      int* __restrict__ ctrs) {
  __shared__ int l_cnt, l_base;
  int t = threadIdx.x;
  if (t == 0) l_cnt = 0;
  __syncthreads();
  int w = blockIdx.x * 256 + t;                 // 4 bins per thread
  bool ok = (w < NBINS / 4);
  int4 h4 = ok ? ((const int4*)bh)[w] : make_int4(-1, -1, -1, -1);
  int hv[4] = {h4.x, h4.y, h4.z, h4.w};
  int gv[4], lp[4];
  int2 n0[4];
  #pragma unroll
  for (int s = 0; s < 4; ++s) {
    lp[s] = -1;
    if (hv[s] < 0) gv[s] = ZROW;
    else {
      n0[s] = node[hv[s]];                      // scattered int2 (L3-fed)
      if (n0[s].x < 0) gv[s] = n0[s].y;         // single input
      else             lp[s] = atomicAdd(&l_cnt, 1);
    }
  }
  __syncthreads();
  if (t == 0) l_base = (l_cnt > 0) ? atomicAdd(&ctrs[0], l_cnt) : 0;
  __syncthreads();
  #pragma unroll
  for (int s = 0; s < 4; ++s) {
    if (lp[s] >= 0) {
      int pos = l_base + lp[s];
      if (pos < AUXCAP) { list[pos] = hv[s]; gv[s] = N_VOX + pos; }
      else              { gv[s] = n0[s].y; }    // overflow guard (won't hit)
    }
  }
  if (ok) ((int4*)ginx)[w] = make_int4(gv[0], gv[1], gv[2], gv[3]);
}

// ---- fixup: aux row = f32 sum of chain's input rows (wave per bin) ----------
__global__ __launch_bounds__(256) void fixup_kernel(short* __restrict__ xb,
                                                    const int* __restrict__ list,
                                                    const int2* __restrict__ node,
                                                    const int* __restrict__ ctrs) {
  int n = ctrs[0]; if (n > AUXCAP) n = AUXCAP;
  int wid  = (blockIdx.x * 256 + threadIdx.x) >> 6;
  int lane = threadIdx.x & 63;
  int nw   = gridDim.x * 4;
  for (int i = wid; i < n; i += nw) {
    int h = list[i];
    float acc = 0.f;
    while (h >= 0) {
      int2 nd = node[h];                        // wave-uniform broadcast
      acc += bf2f(xb[(size_t)nd.y * 64 + lane]);
      h = nd.x;
    }
    xb[(size_t)(N_VOX + i) * 64 + lane] = f2bf(acc);
  }
}

// ---- conv: 64 rows/block (16/wave, grid 1564 = 6.1 blocks/CU); per k per
//      wave: 1 row gather + 8 MFMA; DEPTH-3 row prefetch (st[4][2]) + depth-4
//      idx; W[k] LDS dbuf + XOR-swizzle; LBAR barrier; fused BN stats;
//      NO launch-bounds cap (round-7 lesson: capping VGPR kills prefetch) ----
// A lane l: row=l&15, k-slots (l>>4)*8+j (+32);  B lane l: col=l&15, same slots.
// C/D: col=lane&15, row=(lane>>4)*4+reg  [rounds 1-13 proven].
// LDS swizzle: logical byte ^= ((row c)&7)<<4   [rounds 5-13 proven].
#define LOADR(S, ia)                                            \
  { const short* _pa = xb + (size_t)(ia) * 64;                  \
    S[0] = *(const bf16x8*)(_pa + g8);                          \
    S[1] = *(const bf16x8*)(_pa + 32 + g8); }

__global__ __launch_bounds__(256) void conv_out_kernel(const short* __restrict__ xb,
                                                       const short* __restrict__ wt,
                                                       const int* __restrict__ ginx,
                                                       float* __restrict__ out,
                                                       float* __restrict__ stats) {
  __shared__ short lds[2 * 4096];               // 2 x 8 KB W double buffer
  __shared__ float ls[128];
  int t = threadIdx.x, wave = t >> 6, lane = t & 63;
  int g = lane >> 4, c0 = lane & 15, g8 = g * 8;
  int o = blockIdx.x * 64 + wave * 16 + c0;     // this wave's 16 rows

  int rb  = ((c0 * 128 + g * 16) ^ ((c0 & 7) << 4)) >> 1;
  int wb0 = ((t * 32) ^ (((t >> 2) & 7) << 4)) >> 1;
  if (t < 128) ls[t] = 0.f;

  f32x4 acc[4];
  #pragma unroll
  for (int n = 0; n < 4; ++n) { acc[n][0]=0.f; acc[n][1]=0.f; acc[n][2]=0.f; acc[n][3]=0.f; }

  // 4 gather stages (depth-3); all st indices static after full unroll
  bf16x8 st[4][2];
  bf16x8 s0w = *(const bf16x8*)(wt + t * 16);
  bf16x8 s1w = *(const bf16x8*)(wt + t * 16 + 8);
  LOADR(st[0], ginx[o]);                        // row k=0
  LOADR(st[1], ginx[NPAD + o]);                 // row k=1
  LOADR(st[2], ginx[2 * NPAD + o]);             // row k=2
  int i3 = ginx[3 * NPAD + o];                  // idx k=3
  *(bf16x8*)&lds[wb0]     = s0w;
  *(bf16x8*)&lds[wb0 ^ 8] = s1w;
  LBAR();

  int buf = 0;
  #pragma unroll
  for (int k = 0; k < K3; ++k) {
    if (k + 1 < K3) {                           // W stage loads for k+1
      const short* wn = wt + (size_t)(k + 1) * 4096 + t * 16;
      s0w = *(const bf16x8*)(wn);
      s1w = *(const bf16x8*)(wn + 8);
    }
    if (k + 3 < K3) LOADR(st[(k + 3) % 4], i3); // row k+3
    if (k + 4 < K3) i3 = ginx[(size_t)(k + 4) * NPAD + o];   // idx k+4
    // compute k from lds[buf] with stage st[k%4]
    const short* lb = lds + buf * 4096;
    #pragma unroll
    for (int n = 0; n < 4; ++n) {
      bf16x8 b0 = *(const bf16x8*)&lb[rb + n * 1024];
      bf16x8 b1 = *(const bf16x8*)&lb[(rb ^ 32) + n * 1024];
      acc[n] = __builtin_amdgcn_mfma_f32_16x16x32_bf16(st[k % 4][0], b0, acc[n], 0, 0, 0);
      acc[n] = __builtin_amdgcn_mfma_f32_16x16x32_bf16(st[k % 4][1], b1, acc[n], 0, 0, 0);
    }
    if (k + 1 < K3) {                           // publish W k+1
      short* wd = lds + (buf ^ 1) * 4096;
      *(bf16x8*)&wd[wb0]     = s0w;
      *(bf16x8*)&wd[wb0 ^ 8] = s1w;
    }
    LBAR();                                     // LDS-only ordering barrier
    buf ^= 1;
  }

  // store: each out row exactly once
  int orow = blockIdx.x * 64 + wave * 16 + (g << 2);
  #pragma unroll
  for (int j = 0; j < 4; ++j) {
    int r = orow + j;
    if (r < N_VOX) {
      float* op = out + (size_t)r * 64 + c0;
      op[0]  = acc[0][j];
      op[16] = acc[1][j];
      op[32] = acc[2][j];
      op[48] = acc[3][j];
    }
  }

  // fused BN stats (padding rows hold exact zeros -> contribute nothing)
  #pragma unroll
  for (int n = 0; n < 4; ++n) {
    float s = 0.f, q = 0.f;
    #pragma unroll
    for (int j = 0; j < 4; ++j) { float v = acc[n][j]; s += v; q += v * v; }
    atomicAdd(&ls[n * 16 + c0], s);
    atomicAdd(&ls[64 + n * 16 + c0], q);
  }
  __syncthreads();
  if (t < 128) unsafeAtomicAdd(&stats[t], ls[t]);
}

// ---- finalize BN + ReLU in place -------------------------------------------
__global__ __launch_bounds__(256) void norm_kernel(float* __restrict__ out,
                                                   const float* __restrict__ stats,
                                                   const float* __restrict__ gamma,
                                                   const float* __restrict__ beta) {
  int i4 = blockIdx.x * 256 + threadIdx.x;
  if (i4 >= N_VOX * 16) return;
  const float invN = 1.0f / (float)N_VOX;
  float4 v = ((const float4*)out)[i4];
  int c0 = (i4 << 2) & 63;
  float r[4] = {v.x, v.y, v.z, v.w};
  #pragma unroll
  for (int j = 0; j < 4; ++j) {
    int c = c0 + j;
    float mean = stats[c] * invN;
    float ex2  = stats[64 + c] * invN;
    float var  = ex2 - mean * mean;
    float scale = gamma[c] * rsqrtf(var + BN_EPS);
    float shift = beta[c] - mean * scale;
    r[j] = fmaxf(r[j] * scale + shift, 0.0f);
  }
  v.x = r[0]; v.y = r[1]; v.z = r[2]; v.w = r[3];
  ((float4*)out)[i4] = v;
}

extern "C" void kernel_launch(void* const* d_in, const int* in_sizes, int n_in,
                              void* d_out, int out_size, void* d_ws, size_t ws_size,
                              hipStream_t stream) {
  const float* x      = (const float*)d_in[0];
  const float* W      = (const float*)d_in[1];
  const float* gamma  = (const float*)d_in[2];
  const float* beta   = (const float*)d_in[3];
  const int*   in_idx = (const int*)d_in[4];
  const int*   out_idx= (const int*)d_in[5];
  float* out = (float*)d_out;

  char* ws = (char*)d_ws;
  short* wt    = (short*)(ws + OFF_WT);
  float* stats = (float*)(ws + OFF_STATS);
  int*   ctrs  = (int*)(ws + OFF_CTRS);
  int*   ginx  = (int*)(ws + OFF_GINX);
  int2*  node  = (int2*)(ws + OFF_NODE);
  int*   list  = (int*)(ws + OFF_LIST);
  short* xb    = (short*)(ws + OFF_XB);
  int*   bh    = (int*)(ws + OFF_BH);           // aliased into xb aux region

  hipMemsetAsync(ws + OFF_STATS, 0, OFF_GINX - OFF_STATS, stream);  // stats+ctrs
  hipMemsetAsync((void*)bh, 0xFF, (size_t)NBINS * 4, stream);       // heads = -1

  init_kernel<<<GRID_IN, 256, 0, stream>>>(W, x, wt, xb);
  build_kernel<<<NB_BUILD, 256, 0, stream>>>(in_idx, out_idx, bh, node);
  compact_kernel<<<(NBINS / 4 + 255) / 256, 256, 0, stream>>>(bh, node, ginx, list, ctrs);
  fixup_kernel<<<2048, 256, 0, stream>>>(xb, list, node, ctrs);
  conv_out_kernel<<<NPAD / 64, 256, 0, stream>>>(xb, wt, ginx, out, stats);
  norm_kernel<<<(N_VOX * 16 + 255) / 256, 256, 0, stream>>>(out, stats, gamma, beta);
}

// Round 15
// 222.204 us; speedup vs baseline: 1.0088x; 1.0088x over previous
//
#include <hip/hip_runtime.h>

// Sparse conv block, output-major, int32 exch-chain (round 15):
//   = round 13 (best: 213.8us) with ONE change: EXEC-MASKED gathers.
//   Empty bins keep ginx = -1; conv zero-inits A-fragments and loads only
//   where ia >= 0 -> masked lanes issue NO memory transactions. 66% of all
//   (k,o) bins are empty, and conv is TCP-scatter-issue bound (round 14
//   evidence: 2x occupancy made it slower), so cutting 2/3 of gather
//   line-transactions attacks the measured floor directly.
//   init / build / compact(-1 for empty) / fixup / norm unchanged.
//                                                  MI355X / gfx950.

#define N_VOX   100000
#define NPAD    100096                  // multiple of 64
#define K3      27
#define M_PAIRS 40000
#define NPAIRS  (K3 * M_PAIRS)          // 1,080,000
#define BN_EPS  1e-5f
#define NBINS   (K3 * NPAD)             // 2,702,592
#define AUXMAX  184320                  // E[cnt>=2 bins] = 166.2k
#define AUXCAP  (AUXMAX - 1)
#define ZROW    (N_VOX + AUXMAX - 1)    // zeroed row (legacy; kept, unused)

// ---- workspace layout (bytes) — round-11/13 proven fit ----------------------
#define OFF_WT     0u                       // bf16 Wt[k][c][i]        221,184
#define OFF_STATS  221184u                  // f32[128]
#define OFF_CTRS   221696u                  // [0]=aux counter
#define OFF_GINX   221760u                  // int ginx[NBINS]      10,810,368
#define OFF_NODE   11032128u                // int2 node[NPAIRS]     8,640,000
#define OFF_LIST   19672128u                // int list[AUXMAX]        737,280
#define OFF_XB     20409472u                // bf16 rows[N_VOX+AUXMAX][64]
// bh aliased into xb's AUX region (dead after compact; fixup writes aux slots
// only after compact; ZROW is far beyond bh's end)
#define OFF_BH     (OFF_XB + 12800000u)     // int bh[NBINS]        10,810,368
#define WS_NEED    ((size_t)OFF_XB + (size_t)(N_VOX + AUXMAX) * 128u)

#define NB_WT    432                    // 27*4096/256
#define NB_XB    3125                   // ceil(N_VOX*8/256)
#define GRID_IN  (NB_WT + NB_XB + 1)    // 3558
#define NB_BUILD 4219                   // ceil(NPAIRS/256)

typedef __attribute__((ext_vector_type(8))) short bf16x8;
typedef __attribute__((ext_vector_type(4))) float f32x4;

// LDS-ordering-only barrier: global loads (vmcnt) stay in flight across the
// barrier; compiler still inserts vmcnt(N) before each consuming MFMA.
#define LBAR() asm volatile("s_waitcnt lgkmcnt(0)\n\ts_barrier" ::: "memory")

__device__ __forceinline__ short f2bf(float f) {
  unsigned u = __builtin_bit_cast(unsigned, f);
  u += 0x7FFFu + ((u >> 16) & 1u);
  return (short)(u >> 16);
}
__device__ __forceinline__ float bf2f(short s) {
  unsigned u = ((unsigned)(unsigned short)s) << 16;
  return __builtin_bit_cast(float, u);
}

// ---- init: pure streaming ---------------------------------------------------
__global__ __launch_bounds__(256) void init_kernel(const float* __restrict__ W,
                                                   const float* __restrict__ x,
                                                   short* __restrict__ wt,
                                                   short* __restrict__ xb) {
  int b = blockIdx.x, t = threadIdx.x;
  if (b < NB_WT) {
    int id = b * 256 + t;
    int k = id >> 12, rem = id & 4095, c = rem >> 6, i = rem & 63;
    wt[id] = f2bf(W[(k << 12) + (i << 6) + c]);     // wt[k][c][i]
  } else if (b < NB_WT + NB_XB) {
    int id = (b - NB_WT) * 256 + t;
    if (id < N_VOX * 8) {
      float4 lo = ((const float4*)x)[id * 2];
      float4 hi = ((const float4*)x)[id * 2 + 1];
      bf16x8 v;
      v[0] = f2bf(lo.x); v[1] = f2bf(lo.y); v[2] = f2bf(lo.z); v[3] = f2bf(lo.w);
      v[4] = f2bf(hi.x); v[5] = f2bf(hi.y); v[6] = f2bf(hi.z); v[7] = f2bf(hi.w);
      ((bf16x8*)xb)[id] = v;
    }
  } else {
    if (t < 8) {
      bf16x8 z = {0, 0, 0, 0, 0, 0, 0, 0};
      ((bf16x8*)(xb + (size_t)ZROW * 64))[t] = z;   // harmless; unused now
    }
  }
}

// ---- build: atomics only, int32 heads (L2-resident working window) ----------
__global__ __launch_bounds__(256) void build_kernel(const int* __restrict__ in_idx,
                                                    const int* __restrict__ out_idx,
                                                    int* __restrict__ bh,
                                                    int2* __restrict__ node) {
  int id = blockIdx.x * 256 + threadIdx.x;
  if (id >= NPAIRS) return;
  int k  = id / M_PAIRS;
  int in = in_idx[id];
  int o  = out_idx[id];
  int bb = k * NPAD + o;
  int old = atomicExch(&bh[bb], id);
  node[id] = make_int2(old, in);                // {prev, in}, coalesced
}

// ---- compact: coalesced head read; 1 scattered node read per non-empty bin --
//   empty -> -1 (conv masks the gather) ; single -> in ; multi -> aux slot
__global__ __launch_bounds__(256) void compact_kernel(const int* __restrict__ bh,
                                                      const int2* __restrict__ node,
                                                      int* __restrict__ ginx,
                                                      int* __restrict__ list,
                                                      int* __restrict__ ctrs) {
  __shared__ int l_cnt, l_base;
  int t = threadIdx.x;
  if (t == 0) l_cnt = 0;
  __syncthreads();
  int w = blockIdx.x * 256 + t;                 // 4 bins per thread
  bool ok = (w < NBINS / 4);
  int4 h4 = ok ? ((const int4*)bh)[w] : make_int4(-1, -1, -1, -1);
  int hv[4] = {h4.x, h4.y, h4.z, h4.w};
  int gv[4], lp[4];
  int2 n0[4];
  #pragma unroll
  for (int s = 0; s < 4; ++s) {
    lp[s] = -1;
    if (hv[s] < 0) gv[s] = -1;                  // empty stays -1 (masked in conv)
    else {
      n0[s] = node[hv[s]];                      // scattered int2 (L3-fed)
      if (n0[s].x < 0) gv[s] = n0[s].y;         // single input
      else             lp[s] = atomicAdd(&l_cnt, 1);
    }
  }
  __syncthreads();
  if (t == 0) l_base = (l_cnt > 0) ? atomicAdd(&ctrs[0], l_cnt) : 0;
  __syncthreads();
  #pragma unroll
  for (int s = 0; s < 4; ++s) {
    if (lp[s] >= 0) {
      int pos = l_base + lp[s];
      if (pos < AUXCAP) { list[pos] = hv[s]; gv[s] = N_VOX + pos; }
      else              { gv[s] = n0[s].y; }    // overflow guard (won't hit)
    }
  }
  if (ok) ((int4*)ginx)[w] = make_int4(gv[0], gv[1], gv[2], gv[3]);
}

// ---- fixup: aux row = f32 sum of chain's input rows (wave per bin) ----------
__global__ __launch_bounds__(256) void fixup_kernel(short* __restrict__ xb,
                                                    const int* __restrict__ list,
                                                    const int2* __restrict__ node,
                                                    const int* __restrict__ ctrs) {
  int n = ctrs[0]; if (n > AUXCAP) n = AUXCAP;
  int wid  = (blockIdx.x * 256 + threadIdx.x) >> 6;
  int lane = threadIdx.x & 63;
  int nw   = gridDim.x * 4;
  for (int i = wid; i < n; i += nw) {
    int h = list[i];
    float acc = 0.f;
    while (h >= 0) {
      int2 nd = node[h];                        // wave-uniform broadcast
      acc += bf2f(xb[(size_t)nd.y * 64 + lane]);
      h = nd.x;
    }
    xb[(size_t)(N_VOX + i) * 64 + lane] = f2bf(acc);
  }
}

// ---- conv: 128 rows/block (32/wave, round-13 proven); per k per wave:
//      EXEC-MASKED gathers (empty lanes issue no transactions) + 16 MFMA;
//      depth-2 row prefetch (3 stages); W[k] LDS dbuf + XOR-swizzle; LBAR;
//      fused BN stats --------------------------------------------------------
// A lane l: row=l&15, k-slots (l>>4)*8+j (+32);  B lane l: col=l&15, same slots.
// C/D: col=lane&15, row=(lane>>4)*4+reg  [rounds 1-14 proven].
// LDS swizzle: logical byte ^= ((row c)&7)<<4   [rounds 5-14 proven].
#define LOADST(S, ia, ib)                                       \
  { S[0] = z8; S[1] = z8; S[2] = z8; S[3] = z8;                 \
    if ((ia) >= 0) {                                            \
      const short* _pa = xb + (size_t)(ia) * 64;                \
      S[0] = *(const bf16x8*)(_pa + g8);                        \
      S[1] = *(const bf16x8*)(_pa + 32 + g8);                   \
    }                                                           \
    if ((ib) >= 0) {                                            \
      const short* _pb = xb + (size_t)(ib) * 64;                \
      S[2] = *(const bf16x8*)(_pb + g8);                        \
      S[3] = *(const bf16x8*)(_pb + 32 + g8);                   \
    } }

__global__ __launch_bounds__(256) void conv_out_kernel(const short* __restrict__ xb,
                                                       const short* __restrict__ wt,
                                                       const int* __restrict__ ginx,
                                                       float* __restrict__ out,
                                                       float* __restrict__ stats) {
  __shared__ short lds[2 * 4096];               // 2 x 8 KB W double buffer
  __shared__ float ls[128];
  int t = threadIdx.x, wave = t >> 6, lane = t & 63;
  int g = lane >> 4, c0 = lane & 15, g8 = g * 8;
  int o0 = blockIdx.x * 128 + wave * 32 + c0;   // rows 0..15 of this wave
  int o1 = o0 + 16;                             // rows 16..31

  int rb  = ((c0 * 128 + g * 16) ^ ((c0 & 7) << 4)) >> 1;
  int wb0 = ((t * 32) ^ (((t >> 2) & 7) << 4)) >> 1;
  if (t < 128) ls[t] = 0.f;

  const bf16x8 z8 = {0, 0, 0, 0, 0, 0, 0, 0};
  f32x4 acc0[4], acc1[4];
  #pragma unroll
  for (int n = 0; n < 4; ++n) {
    acc0[n][0]=0.f; acc0[n][1]=0.f; acc0[n][2]=0.f; acc0[n][3]=0.f;
    acc1[n][0]=0.f; acc1[n][1]=0.f; acc1[n][2]=0.f; acc1[n][3]=0.f;
  }

  // 3 gather stages; all st indices static after full unroll
  bf16x8 st[3][4];
  bf16x8 s0w = *(const bf16x8*)(wt + t * 16);
  bf16x8 s1w = *(const bf16x8*)(wt + t * 16 + 8);
  {
    int ia = ginx[o0], ib = ginx[o1];
    LOADST(st[0], ia, ib);                      // rows k=0
    ia = ginx[NPAD + o0]; ib = ginx[NPAD + o1];
    LOADST(st[1], ia, ib);                      // rows k=1
  }
  int i2a = ginx[2 * NPAD + o0], i2b = ginx[2 * NPAD + o1];   // idx k=2
  *(bf16x8*)&lds[wb0]     = s0w;
  *(bf16x8*)&lds[wb0 ^ 8] = s1w;
  LBAR();

  int buf = 0;
  #pragma unroll
  for (int k = 0; k < K3; ++k) {
    if (k + 1 < K3) {                           // W stage loads for k+1
      const short* wn = wt + (size_t)(k + 1) * 4096 + t * 16;
      s0w = *(const bf16x8*)(wn);
      s1w = *(const bf16x8*)(wn + 8);
    }
    if (k + 2 < K3) LOADST(st[(k + 2) % 3], i2a, i2b);   // rows k+2 (masked)
    if (k + 3 < K3) {                           // idx k+3
      i2a = ginx[(size_t)(k + 3) * NPAD + o0];
      i2b = ginx[(size_t)(k + 3) * NPAD + o1];
    }
    // compute k from lds[buf] with stage st[k%3]
    const short* lb = lds + buf * 4096;
    #pragma unroll
    for (int n = 0; n < 4; ++n) {
      bf16x8 b0 = *(const bf16x8*)&lb[rb + n * 1024];
      bf16x8 b1 = *(const bf16x8*)&lb[(rb ^ 32) + n * 1024];
      acc0[n] = __builtin_amdgcn_mfma_f32_16x16x32_bf16(st[k % 3][0], b0, acc0[n], 0, 0, 0);
      acc0[n] = __builtin_amdgcn_mfma_f32_16x16x32_bf16(st[k % 3][1], b1, acc0[n], 0, 0, 0);
      acc1[n] = __builtin_amdgcn_mfma_f32_16x16x32_bf16(st[k % 3][2], b0, acc1[n], 0, 0, 0);
      acc1[n] = __builtin_amdgcn_mfma_f32_16x16x32_bf16(st[k % 3][3], b1, acc1[n], 0, 0, 0);
    }
    if (k + 1 < K3) {                           // publish W k+1
      short* wd = lds + (buf ^ 1) * 4096;
      *(bf16x8*)&wd[wb0]     = s0w;
      *(bf16x8*)&wd[wb0 ^ 8] = s1w;
    }
    LBAR();                                     // LDS-only ordering barrier
    buf ^= 1;
  }

  // store: each out row exactly once
  int orow = blockIdx.x * 128 + wave * 32 + (g << 2);
  #pragma unroll
  for (int j = 0; j < 4; ++j) {
    int r0 = orow + j, r1 = orow + 16 + j;
    if (r0 < N_VOX) {
      float* op = out + (size_t)r0 * 64 + c0;
      op[0] = acc0[0][j]; op[16] = acc0[1][j]; op[32] = acc0[2][j]; op[48] = acc0[3][j];
    }
    if (r1 < N_VOX) {
      float* op = out + (size_t)r1 * 64 + c0;
      op[0] = acc1[0][j]; op[16] = acc1[1][j]; op[32] = acc1[2][j]; op[48] = acc1[3][j];
    }
  }

  // fused BN stats (padding rows hold exact zeros -> contribute nothing)
  #pragma unroll
  for (int n = 0; n < 4; ++n) {
    float s = 0.f, q = 0.f;
    #pragma unroll
    for (int j = 0; j < 4; ++j) {
      float v0 = acc0[n][j], v1 = acc1[n][j];
      s += v0 + v1; q += v0 * v0 + v1 * v1;
    }
    atomicAdd(&ls[n * 16 + c0], s);
    atomicAdd(&ls[64 + n * 16 + c0], q);
  }
  __syncthreads();
  if (t < 128) unsafeAtomicAdd(&stats[t], ls[t]);
}

// ---- finalize BN + ReLU in place -------------------------------------------
__global__ __launch_bounds__(256) void norm_kernel(float* __restrict__ out,
                                                   const float* __restrict__ stats,
                                                   const float* __restrict__ gamma,
                                                   const float* __restrict__ beta) {
  int i4 = blockIdx.x * 256 + threadIdx.x;
  if (i4 >= N_VOX * 16) return;
  const float invN = 1.0f / (float)N_VOX;
  float4 v = ((const float4*)out)[i4];
  int c0 = (i4 << 2) & 63;
  float r[4] = {v.x, v.y, v.z, v.w};
  #pragma unroll
  for (int j = 0; j < 4; ++j) {
    int c = c0 + j;
    float mean = stats[c] * invN;
    float ex2  = stats[64 + c] * invN;
    float var  = ex2 - mean * mean;
    float scale = gamma[c] * rsqrtf(var + BN_EPS);
    float shift = beta[c] - mean * scale;
    r[j] = fmaxf(r[j] * scale + shift, 0.0f);
  }
  v.x = r[0]; v.y = r[1]; v.z = r[2]; v.w = r[3];
  ((float4*)out)[i4] = v;
}

extern "C" void kernel_launch(void* const* d_in, const int* in_sizes, int n_in,
                              void* d_out, int out_size, void* d_ws, size_t ws_size,
                              hipStream_t stream) {
  const float* x      = (const float*)d_in[0];
  const float* W      = (const float*)d_in[1];
  const float* gamma  = (const float*)d_in[2];
  const float* beta   = (const float*)d_in[3];
  const int*   in_idx = (const int*)d_in[4];
  const int*   out_idx= (const int*)d_in[5];
  float* out = (float*)d_out;

  char* ws = (char*)d_ws;
  short* wt    = (short*)(ws + OFF_WT);
  float* stats = (float*)(ws + OFF_STATS);
  int*   ctrs  = (int*)(ws + OFF_CTRS);
  int*   ginx  = (int*)(ws + OFF_GINX);
  int2*  node  = (int2*)(ws + OFF_NODE);
  int*   list  = (int*)(ws + OFF_LIST);
  short* xb    = (short*)(ws + OFF_XB);
  int*   bh    = (int*)(ws + OFF_BH);           // aliased into xb aux region

  hipMemsetAsync(ws + OFF_STATS, 0, OFF_GINX - OFF_STATS, stream);  // stats+ctrs
  hipMemsetAsync((void*)bh, 0xFF, (size_t)NBINS * 4, stream);       // heads = -1

  init_kernel<<<GRID_IN, 256, 0, stream>>>(W, x, wt, xb);
  build_kernel<<<NB_BUILD, 256, 0, stream>>>(in_idx, out_idx, bh, node);
  compact_kernel<<<(NBINS / 4 + 255) / 256, 256, 0, stream>>>(bh, node, ginx, list, ctrs);
  fixup_kernel<<<2048, 256, 0, stream>>>(xb, list, node, ctrs);
  conv_out_kernel<<<NPAD / 128, 256, 0, stream>>>(xb, wt, ginx, out, stats);
  norm_kernel<<<(N_VOX * 16 + 255) / 256, 256, 0, stream>>>(out, stats, gamma, beta);
}

// Round 17
// 213.545 us; speedup vs baseline: 1.0497x; 1.0405x over previous
//
#include <hip/hip_runtime.h>

// Sparse conv block, output-major, int32 exch-chain (round 17 = round 16 with
// the nontemporal-store compile fix: use ext_vector f32x4, not HIP float4):
//   = round 13 (best: 213.8us) + NON-TEMPORAL output stores (conv writes its
//   25MB exactly once; nt keeps L2 lines available for the random xb gathers
//   that are conv's measured floor). norm's write-back also nt.
//   init / build / compact / fixup unchanged.      MI355X / gfx950.

#define N_VOX   100000
#define NPAD    100096                  // multiple of 64
#define K3      27
#define M_PAIRS 40000
#define NPAIRS  (K3 * M_PAIRS)          // 1,080,000
#define BN_EPS  1e-5f
#define NBINS   (K3 * NPAD)             // 2,702,592
#define AUXMAX  184320                  // E[cnt>=2 bins] = 166.2k
#define AUXCAP  (AUXMAX - 1)
#define ZROW    (N_VOX + AUXMAX - 1)    // zeroed gather row (empty bins)

// ---- workspace layout (bytes) — round-11/13 proven fit ----------------------
#define OFF_WT     0u                       // bf16 Wt[k][c][i]        221,184
#define OFF_STATS  221184u                  // f32[128]
#define OFF_CTRS   221696u                  // [0]=aux counter
#define OFF_GINX   221760u                  // int ginx[NBINS]      10,810,368
#define OFF_NODE   11032128u                // int2 node[NPAIRS]     8,640,000
#define OFF_LIST   19672128u                // int list[AUXMAX]        737,280
#define OFF_XB     20409472u                // bf16 rows[N_VOX+AUXMAX][64]
// bh aliased into xb's AUX region (dead after compact; fixup writes aux slots
// only after compact; ZROW is far beyond bh's end)
#define OFF_BH     (OFF_XB + 12800000u)     // int bh[NBINS]        10,810,368
#define WS_NEED    ((size_t)OFF_XB + (size_t)(N_VOX + AUXMAX) * 128u)

#define NB_WT    432                    // 27*4096/256
#define NB_XB    3125                   // ceil(N_VOX*8/256)
#define GRID_IN  (NB_WT + NB_XB + 1)    // 3558
#define NB_BUILD 4219                   // ceil(NPAIRS/256)

typedef __attribute__((ext_vector_type(8))) short bf16x8;
typedef __attribute__((ext_vector_type(4))) float f32x4;

// LDS-ordering-only barrier: global loads (vmcnt) stay in flight across the
// barrier; compiler still inserts vmcnt(N) before each consuming MFMA.
#define LBAR() asm volatile("s_waitcnt lgkmcnt(0)\n\ts_barrier" ::: "memory")

__device__ __forceinline__ short f2bf(float f) {
  unsigned u = __builtin_bit_cast(unsigned, f);
  u += 0x7FFFu + ((u >> 16) & 1u);
  return (short)(u >> 16);
}
__device__ __forceinline__ float bf2f(short s) {
  unsigned u = ((unsigned)(unsigned short)s) << 16;
  return __builtin_bit_cast(float, u);
}

// ---- init: pure streaming ---------------------------------------------------
__global__ __launch_bounds__(256) void init_kernel(const float* __restrict__ W,
                                                   const float* __restrict__ x,
                                                   short* __restrict__ wt,
                                                   short* __restrict__ xb) {
  int b = blockIdx.x, t = threadIdx.x;
  if (b < NB_WT) {
    int id = b * 256 + t;
    int k = id >> 12, rem = id & 4095, c = rem >> 6, i = rem & 63;
    wt[id] = f2bf(W[(k << 12) + (i << 6) + c]);     // wt[k][c][i]
  } else if (b < NB_WT + NB_XB) {
    int id = (b - NB_WT) * 256 + t;
    if (id < N_VOX * 8) {
      float4 lo = ((const float4*)x)[id * 2];
      float4 hi = ((const float4*)x)[id * 2 + 1];
      bf16x8 v;
      v[0] = f2bf(lo.x); v[1] = f2bf(lo.y); v[2] = f2bf(lo.z); v[3] = f2bf(lo.w);
      v[4] = f2bf(hi.x); v[5] = f2bf(hi.y); v[6] = f2bf(hi.z); v[7] = f2bf(hi.w);
      ((bf16x8*)xb)[id] = v;
    }
  } else {
    if (t < 8) {
      bf16x8 z = {0, 0, 0, 0, 0, 0, 0, 0};
      ((bf16x8*)(xb + (size_t)ZROW * 64))[t] = z;
    }
  }
}

// ---- build: atomics only, int32 heads (L2-resident per-k windows) -----------
__global__ __launch_bounds__(256) void build_kernel(const int* __restrict__ in_idx,
                                                    const int* __restrict__ out_idx,
                                                    int* __restrict__ bh,
                                                    int2* __restrict__ node) {
  int id = blockIdx.x * 256 + threadIdx.x;
  if (id >= NPAIRS) return;
  int k  = id / M_PAIRS;
  int in = in_idx[id];
  int o  = out_idx[id];
  int bb = k * NPAD + o;
  int old = atomicExch(&bh[bb], id);
  node[id] = make_int2(old, in);                // {prev, in}, coalesced
}

// ---- compact: coalesced head read; 1 scattered node read per non-empty bin --
__global__ __launch_bounds__(256) void compact_kernel(const int* __restrict__ bh,
                                                      const int2* __restrict__ node,
                                                      int* __restrict__ ginx,
                                                      int* __restrict__ list,
                                                      int* __restrict__ ctrs) {
  __shared__ int l_cnt, l_base;
  int t = threadIdx.x;
  if (t == 0) l_cnt = 0;
  __syncthreads();
  int w = blockIdx.x * 256 + t;                 // 4 bins per thread
  bool ok = (w < NBINS / 4);
  int4 h4 = ok ? ((const int4*)bh)[w] : make_int4(-1, -1, -1, -1);
  int hv[4] = {h4.x, h4.y, h4.z, h4.w};
  int gv[4], lp[4];
  int2 n0[4];
  #pragma unroll
  for (int s = 0; s < 4; ++s) {
    lp[s] = -1;
    if (hv[s] < 0) gv[s] = ZROW;
    else {
      n0[s] = node[hv[s]];                      // scattered int2 (L3-fed)
      if (n0[s].x < 0) gv[s] = n0[s].y;         // single input
      else             lp[s] = atomicAdd(&l_cnt, 1);
    }
  }
  __syncthreads();
  if (t == 0) l_base = (l_cnt > 0) ? atomicAdd(&ctrs[0], l_cnt) : 0;
  __syncthreads();
  #pragma unroll
  for (int s = 0; s < 4; ++s) {
    if (lp[s] >= 0) {
      int pos = l_base + lp[s];
      if (pos < AUXCAP) { list[pos] = hv[s]; gv[s] = N_VOX + pos; }
      else              { gv[s] = n0[s].y; }    // overflow guard (won't hit)
    }
  }
  if (ok) ((int4*)ginx)[w] = make_int4(gv[0], gv[1], gv[2], gv[3]);
}

// ---- fixup: aux row = f32 sum of chain's input rows (wave per bin) ----------
__global__ __launch_bounds__(256) void fixup_kernel(short* __restrict__ xb,
                                                    const int* __restrict__ list,
                                                    const int2* __restrict__ node,
                                                    const int* __restrict__ ctrs) {
  int n = ctrs[0]; if (n > AUXCAP) n = AUXCAP;
  int wid  = (blockIdx.x * 256 + threadIdx.x) >> 6;
  int lane = threadIdx.x & 63;
  int nw   = gridDim.x * 4;
  for (int i = wid; i < n; i += nw) {
    int h = list[i];
    float acc = 0.f;
    while (h >= 0) {
      int2 nd = node[h];                        // wave-uniform broadcast
      acc += bf2f(xb[(size_t)nd.y * 64 + lane]);
      h = nd.x;
    }
    xb[(size_t)(N_VOX + i) * 64 + lane] = f2bf(acc);
  }
}

// ---- conv: 128 rows/block (32/wave, round-13 proven); per k per wave:
//      1 gather set + 16 MFMA; depth-2 row prefetch (3 stages); W[k] LDS
//      dbuf + XOR-swizzle; LBAR; NON-TEMPORAL C-stores; fused BN stats -------
// A lane l: row=l&15, k-slots (l>>4)*8+j (+32);  B lane l: col=l&15, same slots.
// C/D: col=lane&15, row=(lane>>4)*4+reg  [rounds 1-15 proven].
// LDS swizzle: logical byte ^= ((row c)&7)<<4   [rounds 5-15 proven].
#define LOADST(S, ia, ib)                                       \
  { const short* _pa = xb + (size_t)(ia) * 64;                  \
    const short* _pb = xb + (size_t)(ib) * 64;                  \
    S[0] = *(const bf16x8*)(_pa + g8);                          \
    S[1] = *(const bf16x8*)(_pa + 32 + g8);                     \
    S[2] = *(const bf16x8*)(_pb + g8);                          \
    S[3] = *(const bf16x8*)(_pb + 32 + g8); }

__global__ __launch_bounds__(256) void conv_out_kernel(const short* __restrict__ xb,
                                                       const short* __restrict__ wt,
                                                       const int* __restrict__ ginx,
                                                       float* __restrict__ out,
                                                       float* __restrict__ stats) {
  __shared__ short lds[2 * 4096];               // 2 x 8 KB W double buffer
  __shared__ float ls[128];
  int t = threadIdx.x, wave = t >> 6, lane = t & 63;
  int g = lane >> 4, c0 = lane & 15, g8 = g * 8;
  int o0 = blockIdx.x * 128 + wave * 32 + c0;   // rows 0..15 of this wave
  int o1 = o0 + 16;                             // rows 16..31

  int rb  = ((c0 * 128 + g * 16) ^ ((c0 & 7) << 4)) >> 1;
  int wb0 = ((t * 32) ^ (((t >> 2) & 7) << 4)) >> 1;
  if (t < 128) ls[t] = 0.f;

  f32x4 acc0[4], acc1[4];
  #pragma unroll
  for (int n = 0; n < 4; ++n) {
    acc0[n][0]=0.f; acc0[n][1]=0.f; acc0[n][2]=0.f; acc0[n][3]=0.f;
    acc1[n][0]=0.f; acc1[n][1]=0.f; acc1[n][2]=0.f; acc1[n][3]=0.f;
  }

  // 3 gather stages; all st indices static after full unroll
  bf16x8 st[3][4];
  bf16x8 s0w = *(const bf16x8*)(wt + t * 16);
  bf16x8 s1w = *(const bf16x8*)(wt + t * 16 + 8);
  {
    int ia = ginx[o0], ib = ginx[o1];
    LOADST(st[0], ia, ib);                      // rows k=0
    ia = ginx[NPAD + o0]; ib = ginx[NPAD + o1];
    LOADST(st[1], ia, ib);                      // rows k=1
  }
  int i2a = ginx[2 * NPAD + o0], i2b = ginx[2 * NPAD + o1];   // idx k=2
  *(bf16x8*)&lds[wb0]     = s0w;
  *(bf16x8*)&lds[wb0 ^ 8] = s1w;
  LBAR();

  int buf = 0;
  #pragma unroll
  for (int k = 0; k < K3; ++k) {
    if (k + 1 < K3) {                           // W stage loads for k+1
      const short* wn = wt + (size_t)(k + 1) * 4096 + t * 16;
      s0w = *(const bf16x8*)(wn);
      s1w = *(const bf16x8*)(wn + 8);
    }
    if (k + 2 < K3) LOADST(st[(k + 2) % 3], i2a, i2b);   // rows k+2
    if (k + 3 < K3) {                           // idx k+3
      i2a = ginx[(size_t)(k + 3) * NPAD + o0];
      i2b = ginx[(size_t)(k + 3) * NPAD + o1];
    }
    // compute k from lds[buf] with stage st[k%3]
    const short* lb = lds + buf * 4096;
    #pragma unroll
    for (int n = 0; n < 4; ++n) {
      bf16x8 b0 = *(const bf16x8*)&lb[rb + n * 1024];
      bf16x8 b1 = *(const bf16x8*)&lb[(rb ^ 32) + n * 1024];
      acc0[n] = __builtin_amdgcn_mfma_f32_16x16x32_bf16(st[k % 3][0], b0, acc0[n], 0, 0, 0);
      acc0[n] = __builtin_amdgcn_mfma_f32_16x16x32_bf16(st[k % 3][1], b1, acc0[n], 0, 0, 0);
      acc1[n] = __builtin_amdgcn_mfma_f32_16x16x32_bf16(st[k % 3][2], b0, acc1[n], 0, 0, 0);
      acc1[n] = __builtin_amdgcn_mfma_f32_16x16x32_bf16(st[k % 3][3], b1, acc1[n], 0, 0, 0);
    }
    if (k + 1 < K3) {                           // publish W k+1
      short* wd = lds + (buf ^ 1) * 4096;
      *(bf16x8*)&wd[wb0]     = s0w;
      *(bf16x8*)&wd[wb0 ^ 8] = s1w;
    }
    LBAR();                                     // LDS-only ordering barrier
    buf ^= 1;
  }

  // store: each out row exactly once (non-temporal: write-once data, keep L2
  // lines for the random xb gathers that bound this kernel)
  int orow = blockIdx.x * 128 + wave * 32 + (g << 2);
  #pragma unroll
  for (int j = 0; j < 4; ++j) {
    int r0 = orow + j, r1 = orow + 16 + j;
    if (r0 < N_VOX) {
      float* op = out + (size_t)r0 * 64 + c0;
      __builtin_nontemporal_store(acc0[0][j], op);
      __builtin_nontemporal_store(acc0[1][j], op + 16);
      __builtin_nontemporal_store(acc0[2][j], op + 32);
      __builtin_nontemporal_store(acc0[3][j], op + 48);
    }
    if (r1 < N_VOX) {
      float* op = out + (size_t)r1 * 64 + c0;
      __builtin_nontemporal_store(acc1[0][j], op);
      __builtin_nontemporal_store(acc1[1][j], op + 16);
      __builtin_nontemporal_store(acc1[2][j], op + 32);
      __builtin_nontemporal_store(acc1[3][j], op + 48);
    }
  }

  // fused BN stats (padding rows hold exact zeros -> contribute nothing)
  #pragma unroll
  for (int n = 0; n < 4; ++n) {
    float s = 0.f, q = 0.f;
    #pragma unroll
    for (int j = 0; j < 4; ++j) {
      float v0 = acc0[n][j], v1 = acc1[n][j];
      s += v0 + v1; q += v0 * v0 + v1 * v1;
    }
    atomicAdd(&ls[n * 16 + c0], s);
    atomicAdd(&ls[64 + n * 16 + c0], q);
  }
  __syncthreads();
  if (t < 128) unsafeAtomicAdd(&stats[t], ls[t]);
}

// ---- finalize BN + ReLU in place (nt write-back via ext_vector f32x4) -------
__global__ __launch_bounds__(256) void norm_kernel(float* __restrict__ out,
                                                   const float* __restrict__ stats,
                                                   const float* __restrict__ gamma,
                                                   const float* __restrict__ beta) {
  int i4 = blockIdx.x * 256 + threadIdx.x;
  if (i4 >= N_VOX * 16) return;
  const float invN = 1.0f / (float)N_VOX;
  f32x4 v = ((const f32x4*)out)[i4];
  int c0 = (i4 << 2) & 63;
  #pragma unroll
  for (int j = 0; j < 4; ++j) {
    int c = c0 + j;
    float mean = stats[c] * invN;
    float ex2  = stats[64 + c] * invN;
    float var  = ex2 - mean * mean;
    float scale = gamma[c] * rsqrtf(var + BN_EPS);
    float shift = beta[c] - mean * scale;
    v[j] = fmaxf(v[j] * scale + shift, 0.0f);
  }
  __builtin_nontemporal_store(v, (f32x4*)out + i4);
}

extern "C" void kernel_launch(void* const* d_in, const int* in_sizes, int n_in,
                              void* d_out, int out_size, void* d_ws, size_t ws_size,
                              hipStream_t stream) {
  const float* x      = (const float*)d_in[0];
  const float* W      = (const float*)d_in[1];
  const float* gamma  = (const float*)d_in[2];
  const float* beta   = (const float*)d_in[3];
  const int*   in_idx = (const int*)d_in[4];
  const int*   out_idx= (const int*)d_in[5];
  float* out = (float*)d_out;

  char* ws = (char*)d_ws;
  short* wt    = (short*)(ws + OFF_WT);
  float* stats = (float*)(ws + OFF_STATS);
  int*   ctrs  = (int*)(ws + OFF_CTRS);
  int*   ginx  = (int*)(ws + OFF_GINX);
  int2*  node  = (int2*)(ws + OFF_NODE);
  int*   list  = (int*)(ws + OFF_LIST);
  short* xb    = (short*)(ws + OFF_XB);
  int*   bh    = (int*)(ws + OFF_BH);           // aliased into xb aux region

  hipMemsetAsync(ws + OFF_STATS, 0, OFF_GINX - OFF_STATS, stream);  // stats+ctrs
  hipMemsetAsync((void*)bh, 0xFF, (size_t)NBINS * 4, stream);       // heads = -1

  init_kernel<<<GRID_IN, 256, 0, stream>>>(W, x, wt, xb);
  build_kernel<<<NB_BUILD, 256, 0, stream>>>(in_idx, out_idx, bh, node);
  compact_kernel<<<(NBINS / 4 + 255) / 256, 256, 0, stream>>>(bh, node, ginx, list, ctrs);
  fixup_kernel<<<2048, 256, 0, stream>>>(xb, list, node, ctrs);
  conv_out_kernel<<<NPAD / 128, 256, 0, stream>>>(xb, wt, ginx, out, stats);
  norm_kernel<<<(N_VOX * 16 + 255) / 256, 256, 0, stream>>>(out, stats, gamma, beta);
}